// Round 6
// baseline (6753.436 us; speedup 1.0000x reference)
//
#include <hip/hip_runtime.h>
#include <hip/hip_bf16.h>
#include <hip/hip_cooperative_groups.h>

namespace cg = cooperative_groups;

typedef __attribute__((ext_vector_type(8))) short bf16x8;
typedef __attribute__((ext_vector_type(4))) float f32x4;

#define T_STEPS 256
#define BATCH   64
#define KDIM    1024
#define HDIM    1024
#define NGATE   3072   // 3*HDIM
#define LAYERS  3
#define NWG     64
#define SLOTE   (BATCH * HDIM)   // elements per h ring slot

// ---------- helpers ----------
__device__ __forceinline__ unsigned short f2b(float f) {
  union { float f; unsigned int u; } a; a.f = f;
  unsigned int u = a.u;
  unsigned int r = (u + 0x7FFFu + ((u >> 16) & 1u)) >> 16;  // RNE
  return (unsigned short)r;
}
__device__ __forceinline__ float b2f(unsigned short h) {
  union { unsigned int u; float f; } a; a.u = ((unsigned int)h) << 16;
  return a.f;
}
__device__ __forceinline__ void gload16(const void* gptr, void* ldsptr) {
  __builtin_amdgcn_global_load_lds(
      (const __attribute__((address_space(1))) unsigned int*)gptr,
      (__attribute__((address_space(3))) unsigned int*)ldsptr,
      16, 0, 0);
}

// ---------- fp32 -> bf16 bulk convert (4 elems/thread) ----------
__global__ void f2b_kernel(const float* __restrict__ src,
                           unsigned short* __restrict__ dst, int n4) {
  int i = blockIdx.x * blockDim.x + threadIdx.x;
  if (i < n4) {
    float4 v = ((const float4*)src)[i];
    ushort4 o;
    o.x = f2b(v.x); o.y = f2b(v.y); o.z = f2b(v.z); o.w = f2b(v.w);
    ((ushort4*)dst)[i] = o;
  }
}

// ---------- swizzle whh into MFMA B-fragment-major layout ----------
// out layout: [l][ntile(192)][kc(32)][lane(64)][8 bf16]
__global__ void swizzle_whh(const float* __restrict__ whh,
                            unsigned short* __restrict__ out) {
  long gid = (long)blockIdx.x * 256 + threadIdx.x;   // < 3*192*32*64
  int lane = (int)(gid & 63);
  long rest = gid >> 6;
  int kc = (int)(rest & 31); rest >>= 5;
  int ntile = (int)(rest % 192); int l = (int)(rest / 192);
  int n  = ntile * 16 + (lane & 15);
  int k0 = kc * 32 + (lane >> 4) * 8;
  const float* src = whh + (((long)l * NGATE + n) * KDIM + k0);
  unsigned short o[8];
#pragma unroll
  for (int j = 0; j < 8; j++) o[j] = f2b(src[j]);
  bf16x8 v = *(bf16x8*)o;
  *(bf16x8*)(out + gid * 8) = v;
}

// ---------- gi GEMM: C[M,N] = A[M,K] * B[N,K]^T + bias ----------
#define BM 128
#define BN 128
#define BK 32
__global__ __launch_bounds__(256) void gemm_gi(
    const unsigned short* __restrict__ A,   // [M][K] bf16
    const unsigned short* __restrict__ B,   // [N][K] bf16
    const float* __restrict__ bias,         // [N]
    unsigned short* __restrict__ C,         // [M][N] bf16
    int M, int N, int K) {
  __shared__ alignas(16) unsigned short As[BM * BK];
  __shared__ alignas(16) unsigned short Bs[BN * BK];
  int tid = threadIdx.x;
  int wave = tid >> 6, lane = tid & 63;
  int m0 = blockIdx.x * BM, n0 = blockIdx.y * BN;
  int wr = (wave >> 1) * 64, wc = (wave & 1) * 64;

  f32x4 acc[4][4] = {};

  const unsigned short* Ab = A + (long)m0 * K;
  const unsigned short* Bb = B + (long)n0 * K;
  int r0 = tid >> 2, g0 = (tid & 3) * 8;

  for (int k0 = 0; k0 < K; k0 += BK) {
    gload16(Ab + (long)r0 * K + k0 + g0,        &As[(size_t)tid * 8]);
    gload16(Ab + (long)(r0 + 64) * K + k0 + g0, &As[(size_t)(256 + tid) * 8]);
    gload16(Bb + (long)r0 * K + k0 + g0,        &Bs[(size_t)tid * 8]);
    gload16(Bb + (long)(r0 + 64) * K + k0 + g0, &Bs[(size_t)(256 + tid) * 8]);
    __syncthreads();
    bf16x8 af[4], bf[4];
#pragma unroll
    for (int i = 0; i < 4; i++)
      af[i] = *(const bf16x8*)&As[(wr + i * 16 + (lane & 15)) * BK + (lane >> 4) * 8];
#pragma unroll
    for (int j = 0; j < 4; j++)
      bf[j] = *(const bf16x8*)&Bs[(wc + j * 16 + (lane & 15)) * BK + (lane >> 4) * 8];
#pragma unroll
    for (int i = 0; i < 4; i++)
#pragma unroll
      for (int j = 0; j < 4; j++)
        acc[i][j] = __builtin_amdgcn_mfma_f32_16x16x32_bf16(af[i], bf[j], acc[i][j], 0, 0, 0);
    __syncthreads();
  }

#pragma unroll
  for (int j = 0; j < 4; j++) {
    int col = n0 + wc + j * 16 + (lane & 15);
    float bv = bias[col];
#pragma unroll
    for (int i = 0; i < 4; i++) {
      int rbase = m0 + wr + i * 16 + ((lane >> 4) << 2);
      f32x4 v = acc[i][j];
#pragma unroll
      for (int r = 0; r < 4; r++)
        C[(long)(rbase + r) * N + col] = f2b(v[r] + bv);
    }
  }
}

// ---------- GRU recurrence, ring-buffer variant (primary) ----------
// Plain launch, 64 wgs x 256 thr. wg g owns output cols [16g,16g+16) for all 3 gates.
// h exchanged via 257-slot ring: step t reads slot (T-t) [= h(t)], writes slot
// (T-t-1) [= h(t+1)]. Every read address is first-touch within the dispatch ->
// local L2 miss -> fresh from LLC (writes are agent-scope). No cache-maintenance.
// Barrier = 64-entry flag vector: wg g's tid0 STORES flags[g] (no RMW -> no
// serialization); all threads poll lane-per-flag (one coalesced 64-lane load).
__global__ __launch_bounds__(256, 1) void gru_recur_ring(
    const unsigned short* __restrict__ gi,    // [T*B][3072] bf16 (includes b_ih)
    const unsigned short* __restrict__ wsw,   // swizzled whh: [ntile192][kc32][64][8]
    const float* __restrict__ bhh,            // [3072]
    const float* __restrict__ h0,             // [64][1024] fp32
    unsigned short* __restrict__ ring,        // [257][64][1024] bf16
    unsigned short* __restrict__ outseq,      // [T*B][1024] bf16 (layer output)
    float* __restrict__ hout,                 // [64][1024] fp32 -> d_out slice
    unsigned int* __restrict__ flags,         // [64] per-wg progress, monotonic
    unsigned int fbase)                       // progress consumed by prior layers
{
  __shared__ alignas(16) unsigned short Bs[64 * 64 * 8];   // gates r,z B-frags, 64 KB
  int tid = threadIdx.x, wave = tid >> 6, lane = tid & 63;
  int g = blockIdx.x;
  int colc = g * 16 + (lane & 15);
  int rowb = wave * 16 + ((lane >> 4) << 2);

  // ---- preload B gates r,z into LDS ----
#pragma unroll
  for (int i = 0; i < 16; i++) {
    int p = wave * 16 + i;                       // 0..63 = gate*32+kc
    int gate = p >> 5, kc = p & 31;
    const unsigned short* src =
        wsw + ((((long)gate * 64 + g) * 32 + kc) * 64 + lane) * 8;
    gload16(src, &Bs[(size_t)p * 512 + (size_t)lane * 8]);
  }
  // ---- preload B gate n into registers ----
  bf16x8 bn[32];
#pragma unroll
  for (int kc = 0; kc < 32; kc++)
    bn[kc] = *(const bf16x8*)(wsw + ((((long)2 * 64 + g) * 32 + kc) * 64 + lane) * 8);

  // ---- init fp32 h in registers; publish bf16 h0 to ring slot T (agent scope) ----
  float h[4];
  unsigned short* slot0 = ring + (size_t)T_STEPS * SLOTE;
#pragma unroll
  for (int r = 0; r < 4; r++) {
    h[r] = h0[(rowb + r) * HDIM + colc];
    __hip_atomic_store(slot0 + (rowb + r) * HDIM + colc, f2b(h[r]),
                       __ATOMIC_RELAXED, __HIP_MEMORY_SCOPE_AGENT);
  }
  float bh_r = bhh[0 * HDIM + colc];
  float bh_z = bhh[1 * HDIM + colc];
  float bh_n = bhh[2 * HDIM + colc];

  __syncthreads();   // drains vmcnt: Bs staged + h0 at LLC
  if (tid == 0)
    __hip_atomic_store(&flags[g], fbase + 1u,
                       __ATOMIC_RELAXED, __HIP_MEMORY_SCOPE_AGENT);

  // prefetch gi(0) while the flag vector fills
  unsigned short giv[3][4];
  {
    const unsigned short* gib = gi;
#pragma unroll
    for (int r = 0; r < 4; r++) {
      long grow = (long)(rowb + r) * NGATE;
#pragma unroll
      for (int gate = 0; gate < 3; gate++)
        giv[gate][r] = gib[grow + gate * HDIM + colc];
    }
  }
  // wait: all 64 wgs published h0 (lane c polls flags[c])
  while (__hip_atomic_load(&flags[lane], __ATOMIC_RELAXED,
                           __HIP_MEMORY_SCOPE_AGENT) < fbase + 1u) {}
  __syncthreads();

#pragma unroll 1
  for (int t = 0; t < T_STEPS; t++) {
    // ---- read h(t) from ring slot (T-t): first touch, plain vector loads ----
    const unsigned short* hb = ring + (size_t)(T_STEPS - t) * SLOTE;
    const unsigned short* ha = hb + (size_t)(wave * 16 + (lane & 15)) * HDIM
                                  + (size_t)(lane >> 4) * 8;
    bf16x8 af[32];
#pragma unroll
    for (int kc = 0; kc < 32; kc++)
      af[kc] = *(const bf16x8*)(ha + kc * 32);

    // ---- MFMA: 3 gates x 32 kc ----
    f32x4 acc[3] = {};
#pragma unroll
    for (int kc = 0; kc < 32; kc++) {
      bf16x8 b_r = *(const bf16x8*)&Bs[(size_t)(0 * 32 + kc) * 512 + (size_t)lane * 8];
      bf16x8 b_z = *(const bf16x8*)&Bs[(size_t)(1 * 32 + kc) * 512 + (size_t)lane * 8];
      acc[0] = __builtin_amdgcn_mfma_f32_16x16x32_bf16(af[kc], b_r, acc[0], 0, 0, 0);
      acc[1] = __builtin_amdgcn_mfma_f32_16x16x32_bf16(af[kc], b_z, acc[1], 0, 0, 0);
      acc[2] = __builtin_amdgcn_mfma_f32_16x16x32_bf16(af[kc], bn[kc], acc[2], 0, 0, 0);
    }

    // ---- gates + state update (C/D: col=lane&15, row=(lane>>4)*4+reg) ----
    unsigned short* ob = outseq + (long)t * BATCH * HDIM;
    unsigned short* hn = ring + (size_t)(T_STEPS - 1 - t) * SLOTE;   // slot t+1
#pragma unroll
    for (int r = 0; r < 4; r++) {
      float gr = b2f(giv[0][r]);
      float gz = b2f(giv[1][r]);
      float gn = b2f(giv[2][r]);
      float xr = gr + acc[0][r] + bh_r;
      float xz = gz + acc[1][r] + bh_z;
      float rr = 1.0f / (1.0f + __expf(-xr));
      float zz = 1.0f / (1.0f + __expf(-xz));
      float xn = gn + rr * (acc[2][r] + bh_n);
      float e2 = __expf(-2.0f * xn);
      float nn = (1.0f - e2) / (1.0f + e2);      // tanh
      float hv = (1.0f - zz) * nn + zz * h[r];
      h[r] = hv;
      unsigned short hb16 = f2b(hv);
      ob[(rowb + r) * HDIM + colc] = hb16;                  // plain (next dispatch)
      __hip_atomic_store(hn + (rowb + r) * HDIM + colc, hb16,
                         __ATOMIC_RELAXED, __HIP_MEMORY_SCOPE_AGENT);
      if (t == T_STEPS - 1) hout[(rowb + r) * HDIM + colc] = hv;
    }

    // ---- barrier: drain stores, flag-store arrive, prefetch, flag-vector wait ----
    __syncthreads();                             // all waves' h(t+1) stores at LLC
    if (tid == 0)
      __hip_atomic_store(&flags[g], fbase + (unsigned)(t + 2),
                         __ATOMIC_RELAXED, __HIP_MEMORY_SCOPE_AGENT);
    if (t + 1 < T_STEPS) {
      const unsigned short* gib = gi + (long)(t + 1) * BATCH * NGATE;
#pragma unroll
      for (int r = 0; r < 4; r++) {
        long grow = (long)(rowb + r) * NGATE;
#pragma unroll
        for (int gate = 0; gate < 3; gate++)
          giv[gate][r] = gib[grow + gate * HDIM + colc];
      }
      while (__hip_atomic_load(&flags[lane], __ATOMIC_RELAXED,
                               __HIP_MEMORY_SCOPE_AGENT) < fbase + (unsigned)(t + 2)) {}
    }
    __syncthreads();
  }
}

// ---------- GRU recurrence, cooperative fallback (byte-for-byte Round-2 logic) ----------
__global__ __launch_bounds__(256, 1) void gru_recur_cg(
    const unsigned short* __restrict__ gi,
    const unsigned short* __restrict__ wsw,
    const float* __restrict__ bhh,
    const float* __restrict__ h0,
    unsigned short* __restrict__ hbuf,        // [2][64][1024] bf16
    unsigned short* __restrict__ outseq,
    float* __restrict__ hout)
{
  cg::grid_group grid = cg::this_grid();
  __shared__ alignas(16) unsigned short Bs[64 * 64 * 8];
  int tid = threadIdx.x, wave = tid >> 6, lane = tid & 63;
  int g = blockIdx.x;
  int colc = g * 16 + (lane & 15);
  int rowb = wave * 16 + ((lane >> 4) << 2);

#pragma unroll
  for (int i = 0; i < 16; i++) {
    int p = wave * 16 + i;
    int gate = p >> 5, kc = p & 31;
    const unsigned short* src =
        wsw + ((((long)gate * 64 + g) * 32 + kc) * 64 + lane) * 8;
    gload16(src, &Bs[(size_t)p * 512 + (size_t)lane * 8]);
  }
  bf16x8 bn[32];
#pragma unroll
  for (int kc = 0; kc < 32; kc++)
    bn[kc] = *(const bf16x8*)(wsw + ((((long)2 * 64 + g) * 32 + kc) * 64 + lane) * 8);

  float h[4];
#pragma unroll
  for (int r = 0; r < 4; r++) {
    h[r] = h0[(rowb + r) * HDIM + colc];
    hbuf[(rowb + r) * HDIM + colc] = f2b(h[r]);
  }
  float bh_r = bhh[0 * HDIM + colc];
  float bh_z = bhh[1 * HDIM + colc];
  float bh_n = bhh[2 * HDIM + colc];
  __syncthreads();
  grid.sync();

  int cur = 0;
#pragma unroll 1
  for (int t = 0; t < T_STEPS; t++) {
    const unsigned short* gib = gi + (long)t * BATCH * NGATE;
    unsigned short giv[3][4];
#pragma unroll
    for (int r = 0; r < 4; r++) {
      long grow = (long)(rowb + r) * NGATE;
#pragma unroll
      for (int gate = 0; gate < 3; gate++)
        giv[gate][r] = gib[grow + gate * HDIM + colc];
    }

    const unsigned short* hb = hbuf + (size_t)cur * (BATCH * HDIM);
    const unsigned short* ha = hb + (size_t)(wave * 16 + (lane & 15)) * HDIM
                                  + (size_t)(lane >> 4) * 8;
    bf16x8 af[32];
#pragma unroll
    for (int kc = 0; kc < 32; kc++)
      af[kc] = *(const bf16x8*)(ha + kc * 32);

    f32x4 acc[3] = {};
#pragma unroll
    for (int kc = 0; kc < 32; kc++) {
      bf16x8 b_r = *(const bf16x8*)&Bs[(size_t)(0 * 32 + kc) * 512 + (size_t)lane * 8];
      bf16x8 b_z = *(const bf16x8*)&Bs[(size_t)(1 * 32 + kc) * 512 + (size_t)lane * 8];
      acc[0] = __builtin_amdgcn_mfma_f32_16x16x32_bf16(af[kc], b_r, acc[0], 0, 0, 0);
      acc[1] = __builtin_amdgcn_mfma_f32_16x16x32_bf16(af[kc], b_z, acc[1], 0, 0, 0);
      acc[2] = __builtin_amdgcn_mfma_f32_16x16x32_bf16(af[kc], bn[kc], acc[2], 0, 0, 0);
    }

    unsigned short* ob = outseq + (long)t * BATCH * HDIM;
    unsigned short* hn = hbuf + (size_t)(cur ^ 1) * (BATCH * HDIM);
#pragma unroll
    for (int r = 0; r < 4; r++) {
      float gr = b2f(giv[0][r]);
      float gz = b2f(giv[1][r]);
      float gn = b2f(giv[2][r]);
      float xr = gr + acc[0][r] + bh_r;
      float xz = gz + acc[1][r] + bh_z;
      float rr = 1.0f / (1.0f + __expf(-xr));
      float zz = 1.0f / (1.0f + __expf(-xz));
      float xn = gn + rr * (acc[2][r] + bh_n);
      float e2 = __expf(-2.0f * xn);
      float nn = (1.0f - e2) / (1.0f + e2);
      float hv = (1.0f - zz) * nn + zz * h[r];
      h[r] = hv;
      unsigned short hb16 = f2b(hv);
      ob[(rowb + r) * HDIM + colc] = hb16;
      hn[(rowb + r) * HDIM + colc] = hb16;
      if (t == T_STEPS - 1) hout[(rowb + r) * HDIM + colc] = hv;
    }
    cur ^= 1;
    grid.sync();
  }
}

// ---------- host ----------
extern "C" void kernel_launch(void* const* d_in, const int* in_sizes, int n_in,
                              void* d_out, int out_size, void* d_ws, size_t ws_size,
                              hipStream_t stream) {
  const float* x   = (const float*)d_in[0];
  const float* h0  = (const float*)d_in[1];
  const float* wih = (const float*)d_in[2];
  const float* whh = (const float*)d_in[3];
  const float* bih = (const float*)d_in[4];
  const float* bhh = (const float*)d_in[5];
  float* out = (float*)d_out;

  char* ws = (char*)d_ws;
  unsigned short* xb   = (unsigned short*)ws; ws += (size_t)16384 * 1024 * 2;
  unsigned short* yb   = (unsigned short*)ws; ws += (size_t)16384 * 1024 * 2;
  unsigned short* gib  = (unsigned short*)ws; ws += (size_t)16384 * 3072 * 2;
  unsigned short* wihb = (unsigned short*)ws; ws += (size_t)3 * 3072 * 1024 * 2;
  unsigned short* wsw  = (unsigned short*)ws; ws += (size_t)3 * 3072 * 1024 * 2;
  unsigned short* ring = (unsigned short*)ws; ws += (size_t)(T_STEPS + 1) * SLOTE * 2;
  unsigned int*   flags = (unsigned int*)ws;  ws += 256;
  size_t need = (size_t)(ws - (char*)d_ws);
  bool use_ring = (ws_size >= need);
  unsigned short* hbuf = ring;   // fallback reuses first 256 KB of ring area

  hipMemsetAsync(flags, 0, 256, stream);
  f2b_kernel<<<16384, 256, 0, stream>>>(x,   xb,   16777216 / 4);
  f2b_kernel<<<dim3((9437184 / 4 + 255) / 256), 256, 0, stream>>>(wih, wihb, 9437184 / 4);
  swizzle_whh<<<4608, 256, 0, stream>>>(whh, wsw);

  unsigned short* seq_in = xb;
  unsigned short* seq_out = yb;
  for (int l = 0; l < LAYERS; l++) {
    gemm_gi<<<dim3(16384 / BM, 3072 / BN), 256, 0, stream>>>(
        seq_in, wihb + (size_t)l * NGATE * KDIM, bih + l * NGATE, gib,
        16384, NGATE, KDIM);

    const unsigned short* a_wsw = wsw + (size_t)l * NGATE * KDIM;
    const float* a_bhh = bhh + l * NGATE;
    const float* a_h0  = h0 + (size_t)l * BATCH * HDIM;
    float* a_hout = out + (size_t)l * BATCH * HDIM;

    if (use_ring) {
      gru_recur_ring<<<NWG, 256, 0, stream>>>(
          gib, a_wsw, a_bhh, a_h0, ring, seq_out, a_hout,
          flags, (unsigned int)l * (T_STEPS + 1));
    } else {
      const unsigned short* a_gi = gib;
      unsigned short* a_hbuf = hbuf;
      unsigned short* a_out  = seq_out;
      void* args[] = {&a_gi, &a_wsw, &a_bhh, &a_h0, &a_hbuf, &a_out, &a_hout};
      hipLaunchCooperativeKernel((void*)gru_recur_cg, dim3(NWG), dim3(256), args, 0, stream);
    }

    unsigned short* tmp = seq_in; seq_in = seq_out; seq_out = tmp;
  }
}

// Round 7
// 5173.151 us; speedup vs baseline: 1.3055x; 1.3055x over previous
//
#include <hip/hip_runtime.h>
#include <hip/hip_bf16.h>

typedef __attribute__((ext_vector_type(8))) short bf16x8;
typedef __attribute__((ext_vector_type(4))) float f32x4;

#define T_STEPS 256
#define BATCH   64
#define KDIM    1024
#define HDIM    1024
#define NGATE   3072   // 3*HDIM
#define LAYERS  3
#define SLOTE   (BATCH * HDIM)       // elements per h slot [64][1024]
#define RING_SLOTS (T_STEPS + 1)
#define WSZ     (192L * 32 * 64 * 8) // swizzled weight elems per layer

#define MFMA16(a, b, c) __builtin_amdgcn_mfma_f32_16x16x32_bf16(a, b, c, 0, 0, 0)

// ---------- helpers (byte-identical to R6) ----------
__device__ __forceinline__ unsigned short f2b(float f) {
  union { float f; unsigned int u; } a; a.f = f;
  unsigned int u = a.u;
  unsigned int r = (u + 0x7FFFu + ((u >> 16) & 1u)) >> 16;  // RNE
  return (unsigned short)r;
}
__device__ __forceinline__ void gload16(const void* gptr, void* ldsptr) {
  __builtin_amdgcn_global_load_lds(
      (const __attribute__((address_space(1))) unsigned int*)gptr,
      (__attribute__((address_space(3))) unsigned int*)ldsptr,
      16, 0, 0);
}

// ---------- fp32 -> bf16 bulk convert (4 elems/thread) ----------
__global__ void f2b_kernel(const float* __restrict__ src,
                           unsigned short* __restrict__ dst, int n4) {
  int i = blockIdx.x * blockDim.x + threadIdx.x;
  if (i < n4) {
    float4 v = ((const float4*)src)[i];
    ushort4 o;
    o.x = f2b(v.x); o.y = f2b(v.y); o.z = f2b(v.z); o.w = f2b(v.w);
    ((ushort4*)dst)[i] = o;
  }
}

// ---------- swizzle a [3][3072][1024] fp32 matrix into MFMA B-frag layout ----------
// out: [l][ntile(192)][kc(32)][lane(64)][8 bf16]   (identical to R6's swizzle_whh)
__global__ void swizzle_w(const float* __restrict__ w,
                          unsigned short* __restrict__ out) {
  long gid = (long)blockIdx.x * 256 + threadIdx.x;   // < 3*192*32*64
  int lane = (int)(gid & 63);
  long rest = gid >> 6;
  int kc = (int)(rest & 31); rest >>= 5;
  int ntile = (int)(rest % 192); int l = (int)(rest / 192);
  int n  = ntile * 16 + (lane & 15);
  int k0 = kc * 32 + (lane >> 4) * 8;
  const float* src = w + (((long)l * NGATE + n) * KDIM + k0);
  unsigned short o[8];
#pragma unroll
  for (int j = 0; j < 8; j++) o[j] = f2b(src[j]);
  bf16x8 v = *(bf16x8*)o;
  *(bf16x8*)(out + gid * 8) = v;
}

// ---------- fused 3-layer GRU, PLAIN launch, 192 wgs x 256 thr ----------
// wg = (layer l = blockIdx.x>>6, colgroup g = blockIdx.x&63). 192 blocks on 256
// CUs: all resident immediately (same argument as R4/R6's 64<=256; LDS 64KB and
// VGPRs allow >=1 block/CU). NO cooperative launch (R3/R5 silent-death suspect).
// Dataflow: per-layer 257-slot ring; layer l step t reads own slot (T-t) [h_l(t)]
// and prev layer's slot (T-1-t) [h_{l-1}(t+1) = x_l(t)], writes own slot (T-1-t).
// Every ring read is first-touch per wg -> local L2 miss -> fresh from LLC.
// Sync: R6's proven idiom — agent stores, __syncthreads (vmcnt drain), tid0 flag
// STORE, all-lane poll of 64-flag vector, __syncthreads. Own-layer wait: t+2;
// prev-layer wait: t+3 (for next step t+1).
__global__ __launch_bounds__(256, 1) void gru_fused(
    const unsigned short* __restrict__ xb,     // [T][64][1024] bf16 layer-0 input
    const unsigned short* __restrict__ wswhh,  // [3][WSZ] swizzled Whh
    const unsigned short* __restrict__ wswih,  // [3][WSZ] swizzled Wih
    const float* __restrict__ bih,             // [3][3072]
    const float* __restrict__ bhh,             // [3][3072]
    const float* __restrict__ h0,              // [3][64][1024]
    unsigned short* __restrict__ rings,        // [3][257][64][1024] bf16
    float* __restrict__ hout,                  // [3][64][1024] = d_out
    unsigned int* __restrict__ flags)          // [3][64], memset 0
{
  __shared__ alignas(16) unsigned short Bs[64 * 64 * 8];   // Whh r,z frags (64 KB)
  int l = blockIdx.x >> 6, g = blockIdx.x & 63;
  int tid = threadIdx.x, wave = tid >> 6, lane = tid & 63;
  int colc = g * 16 + (lane & 15);
  int rowb = wave * 16 + ((lane >> 4) << 2);

  const unsigned short* whh_l = wswhh + (size_t)l * WSZ;
  const unsigned short* wih_l = wswih + (size_t)l * WSZ;
  unsigned short* ring_l = rings + (size_t)l * RING_SLOTS * SLOTE;
  const unsigned short* prev_ring = rings + (size_t)(l - 1) * RING_SLOTS * SLOTE;
  unsigned int* fl = flags + l * 64;
  const unsigned int* fp = flags + (l > 0 ? (l - 1) : 0) * 64;

  // ---- stage Whh r,z into LDS (R6-identical) ----
#pragma unroll
  for (int i = 0; i < 16; i++) {
    int p = wave * 16 + i;                     // 0..63 = gate*32+kc
    int gate = p >> 5, kc = p & 31;
    gload16(whh_l + ((((long)gate * 64 + g) * 32 + kc) * 64 + lane) * 8,
            &Bs[(size_t)p * 512 + (size_t)lane * 8]);
  }
  // ---- Whh gate n into registers (R6-identical) ----
  bf16x8 bn[32];
#pragma unroll
  for (int kc = 0; kc < 32; kc++)
    bn[kc] = *(const bf16x8*)(whh_l + ((((long)(2 * 64 + g)) * 32 + kc) * 64 + lane) * 8);

  float bhr = bhh[l * NGATE + 0 * HDIM + colc];
  float bhz = bhh[l * NGATE + 1 * HDIM + colc];
  float bhn = bhh[l * NGATE + 2 * HDIM + colc];
  float bir = bih[l * NGATE + 0 * HDIM + colc];
  float biz = bih[l * NGATE + 1 * HDIM + colc];
  float bin_ = bih[l * NGATE + 2 * HDIM + colc];

  // ---- publish h(0)=h0 into own ring slot T (agent scope) ----
  float h[4];
  unsigned short* slotT = ring_l + (size_t)T_STEPS * SLOTE;
#pragma unroll
  for (int r = 0; r < 4; r++) {
    h[r] = h0[l * SLOTE + (rowb + r) * HDIM + colc];
    __hip_atomic_store(slotT + (rowb + r) * HDIM + colc, f2b(h[r]),
                       __ATOMIC_RELAXED, __HIP_MEMORY_SCOPE_AGENT);
  }
  __syncthreads();   // drains vmcnt: Bs staged + h0 at LLC
  if (tid == 0)
    __hip_atomic_store(&fl[g], 1u, __ATOMIC_RELAXED, __HIP_MEMORY_SCOPE_AGENT);

  // pre-loop wait: own h0 published everywhere; prev layer finished step 0
  while (__hip_atomic_load(&fl[lane], __ATOMIC_RELAXED,
                           __HIP_MEMORY_SCOPE_AGENT) < 1u) {}
  if (l > 0) {
    while (__hip_atomic_load(&fp[lane], __ATOMIC_RELAXED,
                             __HIP_MEMORY_SCOPE_AGENT) < 2u) {}
  }
  __syncthreads();

#pragma unroll 1
  for (int t = 0; t < T_STEPS; t++) {
    // ---- addresses: own h(t) at slot (T-t); x(t) = xb[t] or prev slot (T-1-t) ----
    const unsigned short* ha_b = ring_l + (size_t)(T_STEPS - t) * SLOTE
                                 + (size_t)(wave * 16 + (lane & 15)) * HDIM
                                 + (size_t)(lane >> 4) * 8;
    const unsigned short* xrow = (l == 0)
        ? xb + (size_t)t * SLOTE
        : prev_ring + (size_t)(T_STEPS - 1 - t) * SLOTE;
    const unsigned short* xa_b = xrow + (size_t)(wave * 16 + (lane & 15)) * HDIM
                                      + (size_t)(lane >> 4) * 8;

    // ---- issue all 32 h A-frags up front (R6-proven batching) ----
    bf16x8 ha[32];
#pragma unroll
    for (int kc = 0; kc < 32; kc++)
      ha[kc] = *(const bf16x8*)(ha_b + kc * 32);

    // ---- x GEMV: 4 blocks of 8, Wih r,z,n streamed (L2-resident after step 0) ----
    f32x4 air = {}, aiz = {}, ain = {};
#pragma unroll
    for (int kb = 0; kb < 4; kb++) {
      bf16x8 xa[8];
#pragma unroll
      for (int j = 0; j < 8; j++)
        xa[j] = *(const bf16x8*)(xa_b + (kb * 8 + j) * 32);
#pragma unroll
      for (int j = 0; j < 8; j++) {
        int kc = kb * 8 + j;
        bf16x8 wir = *(const bf16x8*)(wih_l + ((((long)(0 * 64 + g)) * 32 + kc) * 64 + lane) * 8);
        bf16x8 wiz = *(const bf16x8*)(wih_l + ((((long)(1 * 64 + g)) * 32 + kc) * 64 + lane) * 8);
        bf16x8 win = *(const bf16x8*)(wih_l + ((((long)(2 * 64 + g)) * 32 + kc) * 64 + lane) * 8);
        air = MFMA16(xa[j], wir, air);
        aiz = MFMA16(xa[j], wiz, aiz);
        ain = MFMA16(xa[j], win, ain);
      }
    }

    // ---- h GEMV (R6-identical): Whh r,z from LDS, n from regs ----
    f32x4 ahr = {}, ahz = {}, ahn = {};
#pragma unroll
    for (int kc = 0; kc < 32; kc++) {
      bf16x8 whr = *(const bf16x8*)&Bs[(size_t)(0 * 32 + kc) * 512 + (size_t)lane * 8];
      bf16x8 whz = *(const bf16x8*)&Bs[(size_t)(1 * 32 + kc) * 512 + (size_t)lane * 8];
      ahr = MFMA16(ha[kc], whr, ahr);
      ahz = MFMA16(ha[kc], whz, ahz);
      ahn = MFMA16(ha[kc], bn[kc], ahn);
    }

    // ---- gates + state update (C/D: col=lane&15, row=(lane>>4)*4+reg) ----
    unsigned short* hn = ring_l + (size_t)(T_STEPS - 1 - t) * SLOTE;  // h(t+1)
#pragma unroll
    for (int r = 0; r < 4; r++) {
      float xr = air[r] + bir + ahr[r] + bhr;
      float xz = aiz[r] + biz + ahz[r] + bhz;
      float rr = 1.0f / (1.0f + __expf(-xr));
      float zz = 1.0f / (1.0f + __expf(-xz));
      float xn = (ain[r] + bin_) + rr * (ahn[r] + bhn);
      float e2 = __expf(-2.0f * xn);
      float nn = (1.0f - e2) / (1.0f + e2);    // tanh
      float hv = (1.0f - zz) * nn + zz * h[r];
      h[r] = hv;
      __hip_atomic_store(hn + (rowb + r) * HDIM + colc, f2b(hv),
                         __ATOMIC_RELAXED, __HIP_MEMORY_SCOPE_AGENT);
      if (t == T_STEPS - 1) hout[l * SLOTE + (rowb + r) * HDIM + colc] = hv;
    }

    // ---- barrier (R6 idiom): drain, flag-store arrive, flag-vector wait ----
    __syncthreads();                           // all waves' h(t+1) stores at LLC
    if (tid == 0)
      __hip_atomic_store(&fl[g], (unsigned)(t + 2),
                         __ATOMIC_RELAXED, __HIP_MEMORY_SCOPE_AGENT);
    if (t + 1 < T_STEPS) {
      while (__hip_atomic_load(&fl[lane], __ATOMIC_RELAXED,
                               __HIP_MEMORY_SCOPE_AGENT) < (unsigned)(t + 2)) {}
      if (l > 0) {
        while (__hip_atomic_load(&fp[lane], __ATOMIC_RELAXED,
                                 __HIP_MEMORY_SCOPE_AGENT) < (unsigned)(t + 3)) {}
      }
    }
    __syncthreads();
  }
}

// ---------- host ----------
extern "C" void kernel_launch(void* const* d_in, const int* in_sizes, int n_in,
                              void* d_out, int out_size, void* d_ws, size_t ws_size,
                              hipStream_t stream) {
  const float* x   = (const float*)d_in[0];
  const float* h0  = (const float*)d_in[1];
  const float* wih = (const float*)d_in[2];
  const float* whh = (const float*)d_in[3];
  const float* bih = (const float*)d_in[4];
  const float* bhh = (const float*)d_in[5];
  float* out = (float*)d_out;

  char* p = (char*)d_ws;
  unsigned short* xb    = (unsigned short*)p; p += (size_t)T_STEPS * SLOTE * 2;             // 33.6 MB
  unsigned short* wswhh = (unsigned short*)p; p += (size_t)LAYERS * WSZ * 2;                // 18.9 MB
  unsigned short* wswih = (unsigned short*)p; p += (size_t)LAYERS * WSZ * 2;                // 18.9 MB
  unsigned short* rings = (unsigned short*)p; p += (size_t)LAYERS * RING_SLOTS * SLOTE * 2; // 101 MB
  unsigned int*   flags = (unsigned int*)p;   p += 4096;
  // total ~172.5 MB (R4/R6 proved ws_size >= ~239 MB)

  hipMemsetAsync(flags, 0, 4096, stream);
  f2b_kernel<<<16384, 256, 0, stream>>>(x, xb, (T_STEPS * SLOTE) / 4);
  swizzle_w<<<4608, 256, 0, stream>>>(whh, wswhh);
  swizzle_w<<<4608, 256, 0, stream>>>(wih, wswih);

  gru_fused<<<LAYERS * 64, 256, 0, stream>>>(
      xb, wswhh, wswih, bih, bhh, h0, rings, out, flags);
}